// Round 17
// baseline (668.483 us; speedup 1.0000x reference)
//
#include <hip/hip_runtime.h>
#include <hip/hip_bf16.h>

#define D_MODEL   640
#define D_INNER   1280
#define D_STATE   34
#define D_CONV    4
#define DT_RANK   40
#define BATCH     2
#define SEQ       2048
#define XDBL_W    (DT_RANK + 2 * D_STATE)   // 108
#define M_TOTAL   (BATCH * SEQ)             // 4096
#define NCHUNK    4
#define CHLEN     (SEQ / NCHUNK)            // 512
#define NQ        (CHLEN / 4)               // 128 quads per chunk
#define QB        4                         // quads per batch (16 steps)
#define RECW      68                        // record: 34 h_end + 34 P

typedef __attribute__((ext_vector_type(8))) short short8v;   // bf16x8 (4 VGPR)
typedef __attribute__((ext_vector_type(4))) short short4v;   // bf16x4
typedef __attribute__((ext_vector_type(4))) float f32x4;     // MFMA acc / load quad

// Inline-asm 16B load: result FORCED into VGPRs; no compiler waitcnt.
#define LD4(dst, base, immoff) \
    asm volatile("global_load_dwordx4 %0, %1, off offset:" immoff \
                 : "=v"(dst) : "v"(base))

// Split f32 into bf16 hi (truncation) + bf16 lo (RNE of residual).
__device__ __forceinline__ void split_bf16(float x, short& hi, short& lo) {
    unsigned u  = __builtin_bit_cast(unsigned, x);
    unsigned uh = u & 0xFFFF0000u;
    hi = (short)(uh >> 16);
    float r = x - __builtin_bit_cast(float, uh);   // exact
    unsigned v = __builtin_bit_cast(unsigned, r);
    v += 0x7FFFu + ((v >> 16) & 1u);               // RNE to bf16
    lo = (short)(v >> 16);
}

__device__ __forceinline__ void split4(const float4& v, short4v& h, short4v& l) {
    float xs[4] = {v.x, v.y, v.z, v.w};
    #pragma unroll
    for (int j = 0; j < 4; ++j) { short hh, ll; split_bf16(xs[j], hh, ll); h[j] = hh; l[j] = ll; }
}

// ---------------------------------------------------------------------------
// Split-bf16 MFMA GEMM: C[M,N] = A[M,K] . B[N,K]^T  (fp32 in/out, ~fp32 acc).
// MODE: 0 = none, 2 = silu(v) for output rows >= D_INNER (merged in-proj)
// ---------------------------------------------------------------------------
template<int MODE>
__global__ __launch_bounds__(256) void gemm_mfma(
    const float* __restrict__ A, const float* __restrict__ B,
    float* __restrict__ C, int M, int N, int K, int lda, int ldb, int ldc)
{
    constexpr int BMt = 128, BKt = 32;
    constexpr int LDT = 40;                        // LDS row stride in shorts
    __shared__ short Ahi[BMt * LDT], Alo[BMt * LDT];
    __shared__ short Bhi[BMt * LDT], Blo[BMt * LDT];

    const int tid  = threadIdx.x;
    const long m0  = (long)blockIdx.y * BMt;
    const long n0  = (long)blockIdx.x * BMt;
    const int wid  = tid >> 6, lane = tid & 63;
    const int wr   = (wid >> 1) * 64;
    const int wc   = (wid & 1) * 64;
    const int lrow = lane & 15;
    const int lkb  = lane >> 4;

    const bool do_silu = (MODE == 2) && (m0 >= D_INNER);   // block-uniform

    f32x4 acc[4][4] = {};

    for (int k0 = 0; k0 < K; k0 += BKt) {
        __syncthreads();
        #pragma unroll
        for (int q = 0; q < 4; ++q) {
            int flat = tid + q * 256;
            int r  = flat >> 3;
            int f4 = (flat & 7) << 2;
            float4 va = *reinterpret_cast<const float4*>(&A[(m0 + r) * lda + k0 + f4]);
            float4 vb = *reinterpret_cast<const float4*>(&B[(n0 + r) * ldb + k0 + f4]);
            short4v ah, al, bh, bl;
            split4(va, ah, al);
            split4(vb, bh, bl);
            *reinterpret_cast<short4v*>(&Ahi[r * LDT + f4]) = ah;
            *reinterpret_cast<short4v*>(&Alo[r * LDT + f4]) = al;
            *reinterpret_cast<short4v*>(&Bhi[r * LDT + f4]) = bh;
            *reinterpret_cast<short4v*>(&Blo[r * LDT + f4]) = bl;
        }
        __syncthreads();

        short8v a_hi[4], a_lo[4], b_hi[4], b_lo[4];
        #pragma unroll
        for (int i = 0; i < 4; ++i) {
            int ar = (wr + i * 16 + lrow) * LDT + lkb * 8;
            int br = (wc + i * 16 + lrow) * LDT + lkb * 8;
            a_hi[i] = *reinterpret_cast<const short8v*>(&Ahi[ar]);
            a_lo[i] = *reinterpret_cast<const short8v*>(&Alo[ar]);
            b_hi[i] = *reinterpret_cast<const short8v*>(&Bhi[br]);
            b_lo[i] = *reinterpret_cast<const short8v*>(&Blo[br]);
        }
        #pragma unroll
        for (int i = 0; i < 4; ++i)
            #pragma unroll
            for (int j = 0; j < 4; ++j) {
                acc[i][j] = __builtin_amdgcn_mfma_f32_16x16x32_bf16(a_hi[i], b_hi[j], acc[i][j], 0, 0, 0);
                acc[i][j] = __builtin_amdgcn_mfma_f32_16x16x32_bf16(a_hi[i], b_lo[j], acc[i][j], 0, 0, 0);
                acc[i][j] = __builtin_amdgcn_mfma_f32_16x16x32_bf16(a_lo[i], b_hi[j], acc[i][j], 0, 0, 0);
            }
    }

    #pragma unroll
    for (int i = 0; i < 4; ++i) {
        long grow0 = m0 + wr + i * 16 + lkb * 4;
        #pragma unroll
        for (int j = 0; j < 4; ++j) {
            long gcol = n0 + wc + j * 16 + lrow;
            #pragma unroll
            for (int r = 0; r < 4; ++r) {
                float v = acc[i][j][r];
                if (do_silu) v = v * (1.0f / (1.0f + __expf(-v)));
                C[(grow0 + r) * ldc + gcol] = v;
            }
        }
    }
}

// ---------------------------------------------------------------------------
// Small f32 GEMM. A [M,K] (LAYA=0) or [K,M] (LAYA=1); B [N,K] (LAYB=0) or
// [K,N] (LAYB=1). MODE: 0 = none, 2 = softplus(v + bias[gm]).
// ---------------------------------------------------------------------------
#define BM 64
#define BN 64
#define BK 16

template<int LAYA, int LAYB, int MODE>
__global__ __launch_bounds__(256) void gemm_tn(
    const float* __restrict__ A, const float* __restrict__ B,
    float* __restrict__ C, int M, int N, int K, int lda, int ldb, int ldc,
    const float* __restrict__ bias)
{
    __shared__ float As[BK][BM + 4];
    __shared__ float Bs[BK][BN + 4];

    const int tid = threadIdx.x;
    const int m0 = blockIdx.y * BM;
    const int n0 = blockIdx.x * BN;
    const int tx = tid & 15;
    const int ty = tid >> 4;

    float acc[4][4] = {};

    for (int k0 = 0; k0 < K; k0 += BK) {
        #pragma unroll
        for (int i = 0; i < 4; ++i) {
            int idx = tid + i * 256;
            if (LAYA == 0) {
                int r = idx >> 4;
                int c = idx & 15;
                As[c][r] = (m0 + r < M && k0 + c < K)
                         ? A[(long)(m0 + r) * lda + (k0 + c)] : 0.0f;
            } else {
                int c = idx >> 6;
                int r = idx & 63;
                As[c][r] = (m0 + r < M && k0 + c < K)
                         ? A[(long)(k0 + c) * lda + (m0 + r)] : 0.0f;
            }
            if (LAYB == 0) {
                int rb = idx >> 4;
                int cb = idx & 15;
                Bs[cb][rb] = (n0 + rb < N && k0 + cb < K)
                           ? B[(long)(n0 + rb) * ldb + (k0 + cb)] : 0.0f;
            } else {
                int cb = idx >> 6;
                int rb = idx & 63;
                Bs[cb][rb] = (n0 + rb < N && k0 + cb < K)
                           ? B[(long)(k0 + cb) * ldb + (n0 + rb)] : 0.0f;
            }
        }
        __syncthreads();

        #pragma unroll
        for (int k = 0; k < BK; ++k) {
            const float4 a4 = *reinterpret_cast<const float4*>(&As[k][ty * 4]);
            const float4 b4 = *reinterpret_cast<const float4*>(&Bs[k][tx * 4]);
            const float a_[4] = {a4.x, a4.y, a4.z, a4.w};
            const float b_[4] = {b4.x, b4.y, b4.z, b4.w};
            #pragma unroll
            for (int i = 0; i < 4; ++i)
                #pragma unroll
                for (int j = 0; j < 4; ++j)
                    acc[i][j] = fmaf(a_[i], b_[j], acc[i][j]);
        }
        __syncthreads();
    }

    #pragma unroll
    for (int i = 0; i < 4; ++i) {
        int gm = m0 + ty * 4 + i;
        if (gm >= M) continue;
        float bi = (MODE == 2) ? bias[gm] : 0.0f;
        #pragma unroll
        for (int j = 0; j < 4; ++j) {
            int gn = n0 + tx * 4 + j;
            if (gn >= N) continue;
            float v = acc[i][j];
            if (MODE == 2) {
                v += bi;
                v = (v > 15.0f) ? v : log1pf(__expf(v));   // softplus
            }
            C[(long)gm * ldc + gn] = v;
        }
    }
}

// ---------------------------------------------------------------------------
// Split-K f32 GEMM producing TRANSPOSED x_dbl: Cp[z][108][4096].
// ---------------------------------------------------------------------------
__global__ __launch_bounds__(256) void gemm_splitk_T(
    const float* __restrict__ A, const float* __restrict__ B,
    float* __restrict__ Cp, int M, int N, int K, int lda, int ldb, int ldc)
{
    __shared__ float As[BK][BM + 4];
    __shared__ float Bs[BK][BN + 4];

    const int tid = threadIdx.x;
    const int m0 = blockIdx.y * BM;
    const int n0 = blockIdx.x * BN;
    const int z  = blockIdx.z;
    const int kseg = K / 4;
    const int kbeg = z * kseg;
    const int tx = tid & 15;
    const int ty = tid >> 4;

    float acc[4][4] = {};

    for (int k0 = kbeg; k0 < kbeg + kseg; k0 += BK) {
        #pragma unroll
        for (int i = 0; i < 4; ++i) {
            int idx = tid + i * 256;
            int r = idx >> 4;
            int c = idx & 15;
            As[c][r] = (m0 + r < M) ? A[(long)(m0 + r) * lda + (k0 + c)] : 0.0f;
            int cb = idx >> 6;
            int rb = idx & 63;
            Bs[cb][rb] = B[(long)(k0 + cb) * ldb + (n0 + rb)];
        }
        __syncthreads();

        #pragma unroll
        for (int k = 0; k < BK; ++k) {
            const float4 a4 = *reinterpret_cast<const float4*>(&As[k][ty * 4]);
            const float4 b4 = *reinterpret_cast<const float4*>(&Bs[k][tx * 4]);
            const float a_[4] = {a4.x, a4.y, a4.z, a4.w};
            const float b_[4] = {b4.x, b4.y, b4.z, b4.w};
            #pragma unroll
            for (int i = 0; i < 4; ++i)
                #pragma unroll
                for (int j = 0; j < 4; ++j)
                    acc[i][j] = fmaf(a_[i], b_[j], acc[i][j]);
        }
        __syncthreads();
    }

    float* Cz = Cp + (long)z * M * ldc;
    #pragma unroll
    for (int i = 0; i < 4; ++i) {
        int gm = m0 + ty * 4 + i;
        if (gm >= M) continue;
        #pragma unroll
        for (int j = 0; j < 4; ++j) {
            int gn = n0 + tx * 4 + j;
            Cz[(long)gm * ldc + gn] = acc[i][j];
        }
    }
}

// Reduce 4 split-K partials: out[i] = sum_z part[z][i].
__global__ __launch_bounds__(256) void reduce4_kernel(
    const float* __restrict__ part, float* __restrict__ out, int n)
{
    int i4 = (blockIdx.x * 256 + threadIdx.x) * 4;
    if (i4 >= n) return;
    float4 s0 = *reinterpret_cast<const float4*>(&part[i4]);
    float4 s1 = *reinterpret_cast<const float4*>(&part[(long)n + i4]);
    float4 s2 = *reinterpret_cast<const float4*>(&part[(long)2 * n + i4]);
    float4 s3 = *reinterpret_cast<const float4*>(&part[(long)3 * n + i4]);
    float4 r;
    r.x = (s0.x + s1.x) + (s2.x + s3.x);
    r.y = (s0.y + s1.y) + (s2.y + s3.y);
    r.z = (s0.z + s1.z) + (s2.z + s3.z);
    r.w = (s0.w + s1.w) + (s2.w + s3.w);
    *reinterpret_cast<float4*>(&out[i4]) = r;
}

// ---------------------------------------------------------------------------
// Depthwise causal conv (width 4) + bias + SiLU on TRANSPOSED x [1280][4096].
// ---------------------------------------------------------------------------
__global__ __launch_bounds__(256) void conv_silu_kernel(
    const float* __restrict__ xT, const float* __restrict__ cw,
    const float* __restrict__ cb, float* __restrict__ uT)
{
    int idx = blockIdx.x * 256 + threadIdx.x;      // d*4096 + bs
    if (idx >= D_INNER * M_TOTAL) return;
    int bs = idx & (M_TOTAL - 1);
    int d  = idx >> 12;
    int s  = bs & (SEQ - 1);

    const float* xr = xT + idx;
    float acc = cb[d];
    #pragma unroll
    for (int k = 0; k < D_CONV; ++k) {
        int off = k - (D_CONV - 1);                // -3..0
        if (s + off >= 0)
            acc = fmaf(xr[off], cw[d * D_CONV + k], acc);
    }
    uT[idx] = acc * (1.0f / (1.0f + __expf(-acc)));
}

// ---------------------------------------------------------------------------
// LDS-tiled transpose: in [1280][4096] -> out [4096][1280]. 32x32 tiles.
// ---------------------------------------------------------------------------
__global__ __launch_bounds__(256) void transpose_kernel(
    const float* __restrict__ in, float* __restrict__ out)
{
    __shared__ float tile[32][33];
    const int tx = threadIdx.x & 31;
    const int ty = threadIdx.x >> 5;
    const int t0 = blockIdx.x * 32;
    const int d0 = blockIdx.y * 32;

    #pragma unroll
    for (int i = 0; i < 32; i += 8)
        tile[ty + i][tx] = in[(long)(d0 + ty + i) * M_TOTAL + t0 + tx];
    __syncthreads();
    #pragma unroll
    for (int i = 0; i < 32; i += 8)
        out[(long)(t0 + ty + i) * D_INNER + d0 + tx] = tile[tx][ty + i];
}

#define DPP_ADD(X_, CTRL_) {                                                 \
        int t_ = __builtin_amdgcn_update_dpp(                                \
            0, __builtin_bit_cast(int, X_), (CTRL_), 0xf, 0xf, true);        \
        X_ += __builtin_bit_cast(float, t_);                                 \
    }

// ---------------------------------------------------------------------------
// Chunked scan pass 1 (v5, inline-asm batched loads): chunk-local (h_end, P).
// 12 asm loads -> one vmcnt(0) -> 16 steps. No lane masking needed: h/P of
// inactive lanes are garbage-but-finite (A_n=0 -> dA=1) and never stored.
// ---------------------------------------------------------------------------
__global__ __launch_bounds__(64, 4) void scan_part1(
    const float* __restrict__ xdblT,   // [108][4096]; B rows 40..73
    const float* __restrict__ spT,     // softplus(dt+bias)[1280][4096]
    const float* __restrict__ A_log,
    const float* __restrict__ uT,      // u [1280][4096]
    float* __restrict__ rec)
{
    const int cid  = blockIdx.x;                   // bd*(NCHUNK-1) + c
    const int bd   = cid / (NCHUNK - 1);
    const int c    = cid % (NCHUNK - 1);
    const int lane = threadIdx.x;
    const int b = bd / D_INNER;
    const int d = bd % D_INNER;
    const bool act = lane < D_STATE;

    const float A_n = act ? -__expf(A_log[d * D_STATE + lane]) : 0.0f;

    const long tbase = (long)b * SEQ + (long)c * CHLEN;
    const float* sp_p = spT + (long)d * M_TOTAL + tbase;
    const float* u_p  = uT  + (long)d * M_TOTAL + tbase;
    const float* Bp   = xdblT + (long)(act ? DT_RANK + lane : 0) * M_TOTAL + tbase;

    float h = 0.0f, P = 1.0f;

#define ST1(SPX, UX, BX) {                                                   \
        float dA = __expf((SPX) * A_n);                                      \
        h = fmaf(dA, h, ((SPX) * (UX)) * (BX));                              \
        P *= dA;                                                             \
    }
#define STQ1(SP_, U_, B_) {                                                  \
        ST1(SP_[0], U_[0], B_[0]); ST1(SP_[1], U_[1], B_[1]);                \
        ST1(SP_[2], U_[2], B_[2]); ST1(SP_[3], U_[3], B_[3]);                \
    }

    #pragma unroll 1
    for (int q0 = 0; q0 < NQ; q0 += QB) {
        f32x4 S0, S1, S2, S3, U0, U1, U2, U3, B0, B1, B2, B3;
        const float* ps = sp_p + q0 * 4;
        const float* pu = u_p  + q0 * 4;
        const float* pb = Bp   + q0 * 4;
        LD4(S0, ps, "0");  LD4(S1, ps, "16"); LD4(S2, ps, "32"); LD4(S3, ps, "48");
        LD4(U0, pu, "0");  LD4(U1, pu, "16"); LD4(U2, pu, "32"); LD4(U3, pu, "48");
        LD4(B0, pb, "0");  LD4(B1, pb, "16"); LD4(B2, pb, "32"); LD4(B3, pb, "48");
        asm volatile("s_waitcnt vmcnt(0)" ::: "memory");
        __builtin_amdgcn_sched_barrier(0);
        STQ1(S0, U0, B0); STQ1(S1, U1, B1); STQ1(S2, U2, B2); STQ1(S3, U3, B3);
    }
#undef ST1
#undef STQ1

    if (act) {
        rec[(long)cid * RECW + lane]      = h;
        rec[(long)cid * RECW + 34 + lane] = P;
    }
}

// ---------------------------------------------------------------------------
// Chunked scan pass 3 (v5, inline-asm batched loads): per-chunk y scan.
// 20 asm loads -> one vmcnt(0) -> 16 steps. Only C is zero-masked for
// inactive lanes (pp = h*C = 0 kills their contribution to the reduce).
// ---------------------------------------------------------------------------
__global__ __launch_bounds__(64, 4) void scan_part3(
    const float* __restrict__ gT,      // silu(z)          [1280][4096]
    const float* __restrict__ xdblT,   // [108][4096]; B rows 40.., C rows 74..
    const float* __restrict__ spT,     // softplus(dt+bias)[1280][4096]
    const float* __restrict__ A_log,
    const float* __restrict__ D_skip,
    const float* __restrict__ rec,
    float* __restrict__ uT)            // in: u, out: y*g (in-place)
{
    const int cid  = blockIdx.x;                   // bd*NCHUNK + c
    const int bd   = cid >> 2;
    const int c    = cid & (NCHUNK - 1);
    const int lane = threadIdx.x;
    const int b = bd / D_INNER;
    const int d = bd % D_INNER;
    const bool act = lane < D_STATE;

    const float A_n = act ? -__expf(A_log[d * D_STATE + lane]) : 0.0f;
    const float Dd  = D_skip[d];
    const float cmask = act ? 1.0f : 0.0f;

    const long tbase = (long)b * SEQ + (long)c * CHLEN;
    const float* sp_p = spT + (long)d * M_TOTAL + tbase;
    const float* g_p  = gT  + (long)d * M_TOTAL + tbase;
    float*       u_p  = uT  + (long)d * M_TOTAL + tbase;
    const float* Bp   = xdblT + (long)(act ? DT_RANK + lane : 0) * M_TOTAL + tbase;
    const float* Cp   = xdblT + (long)(act ? DT_RANK + D_STATE + lane : 0) * M_TOTAL + tbase;

    // ---- combine prologue: h_start from preceding chunks' records
    float h = 0.0f;
    for (int cc = 0; cc < c; ++cc) {
        long rbase = (long)(bd * (NCHUNK - 1) + cc) * RECW;
        float he = act ? rec[rbase + lane]      : 0.0f;
        float Pp = act ? rec[rbase + 34 + lane] : 0.0f;
        h = fmaf(Pp, h, he);
    }

#define ST(SPX, UX, GX, BX, CX, YX) {                                        \
        float dA = __expf((SPX) * A_n);                                      \
        h = fmaf(dA, h, ((SPX) * (UX)) * (BX));                              \
        float pp = h * (CX) * cmask;                                         \
        DPP_ADD(pp, 0x111);   /* row_shr:1  */                               \
        DPP_ADD(pp, 0x112);   /* row_shr:2  */                               \
        DPP_ADD(pp, 0x114);   /* row_shr:4  */                               \
        DPP_ADD(pp, 0x118);   /* row_shr:8  */                               \
        DPP_ADD(pp, 0x142);   /* row_bcast:15 */                             \
        DPP_ADD(pp, 0x143);   /* row_bcast:31 */                             \
        YX = fmaf((UX), Dd, pp) * (GX);                                      \
    }
#define STQ(SP_, U_, G_, B_, C_, QI) {                                       \
        f32x4 yq;                                                            \
        ST(SP_[0], U_[0], G_[0], B_[0], C_[0], yq[0]);                       \
        ST(SP_[1], U_[1], G_[1], B_[1], C_[1], yq[1]);                       \
        ST(SP_[2], U_[2], G_[2], B_[2], C_[2], yq[2]);                       \
        ST(SP_[3], U_[3], G_[3], B_[3], C_[3], yq[3]);                       \
        if (lane == 63)                                                      \
            *reinterpret_cast<f32x4*>(&u_p[(q0 + (QI)) * 4]) = yq;           \
    }

    #pragma unroll 1
    for (int q0 = 0; q0 < NQ; q0 += QB) {
        f32x4 S0, S1, S2, S3, U0, U1, U2, U3, G0, G1, G2, G3;
        f32x4 B0, B1, B2, B3, C0, C1, C2, C3;
        const float* ps = sp_p + q0 * 4;
        const float* pu = u_p  + q0 * 4;
        const float* pg = g_p  + q0 * 4;
        const float* pb = Bp   + q0 * 4;
        const float* pc = Cp   + q0 * 4;
        LD4(S0, ps, "0");  LD4(S1, ps, "16"); LD4(S2, ps, "32"); LD4(S3, ps, "48");
        LD4(U0, pu, "0");  LD4(U1, pu, "16"); LD4(U2, pu, "32"); LD4(U3, pu, "48");
        LD4(G0, pg, "0");  LD4(G1, pg, "16"); LD4(G2, pg, "32"); LD4(G3, pg, "48");
        LD4(B0, pb, "0");  LD4(B1, pb, "16"); LD4(B2, pb, "32"); LD4(B3, pb, "48");
        LD4(C0, pc, "0");  LD4(C1, pc, "16"); LD4(C2, pc, "32"); LD4(C3, pc, "48");
        asm volatile("s_waitcnt vmcnt(0)" ::: "memory");
        __builtin_amdgcn_sched_barrier(0);
        STQ(S0, U0, G0, B0, C0, 0);
        STQ(S1, U1, G1, B1, C1, 1);
        STQ(S2, U2, G2, B2, C2, 2);
        STQ(S3, U3, G3, B3, C3, 3);
    }
#undef ST
#undef STQ
}

// ---------------------------------------------------------------------------
extern "C" void kernel_launch(void* const* d_in, const int* in_sizes, int n_in,
                              void* d_out, int out_size, void* d_ws, size_t ws_size,
                              hipStream_t stream)
{
    const float* hs      = (const float*)d_in[0];
    const float* W_in    = (const float*)d_in[1];
    const float* conv_w  = (const float*)d_in[2];
    const float* conv_b  = (const float*)d_in[3];
    const float* W_x     = (const float*)d_in[4];
    const float* W_dt    = (const float*)d_in[5];
    const float* dt_bias = (const float*)d_in[6];
    const float* A_log   = (const float*)d_in[7];
    const float* D_skip  = (const float*)d_in[8];
    const float* W_out   = (const float*)d_in[9];
    float* out = (float*)d_out;

    float* ws    = (float*)d_ws;
    float* xT    = ws;                                       // 1280 x 4096 (x; then partials; then yN)
    float* gT    = xT    + (size_t)D_INNER * M_TOTAL;        // 1280 x 4096
    float* uT    = gT    + (size_t)D_INNER * M_TOTAL;        // 1280 x 4096 (u, then y in-place)
    float* xdblT = uT    + (size_t)D_INNER * M_TOTAL;        // 108 x 4096
    float* spT   = xdblT + (size_t)XDBL_W * M_TOTAL;         // 1280 x 4096
    float* rec   = spT   + (size_t)D_INNER * M_TOTAL;        // 2560*3*68 floats
    float* part  = xT;                                       // 4*108*4096 partials (xT dead after conv)
    float* yN    = xT;                                       // 4096 x 1280 (partials dead after reduce)

    dim3 blk(256);

    // 1) merged in-proj: [xT; gT] = W_in @ hs^T  [2560][4096], silu rows>=1280
    gemm_mfma<2><<<dim3(M_TOTAL / 128, (2 * D_INNER) / 128), blk, 0, stream>>>(
        W_in, hs, xT, 2 * D_INNER, M_TOTAL, D_MODEL, D_MODEL, D_MODEL, M_TOTAL);

    // 2) u_T = silu(dwconv(x_T) + cb)     [1280][4096]
    conv_silu_kernel<<<(D_INNER * M_TOTAL + 255) / 256, blk, 0, stream>>>(
        xT, conv_w, conv_b, uT);

    // 3) x_dblT split-K partials: [108][4096] transposed (B/C t-contiguous)
    gemm_splitk_T<<<dim3(M_TOTAL / BN, (XDBL_W + BM - 1) / BM, 4), blk, 0, stream>>>(
        W_x, uT, part, XDBL_W, M_TOTAL, D_INNER, D_INNER, M_TOTAL, M_TOTAL);

    // 3b) xdblT = sum of 4 partials
    reduce4_kernel<<<(XDBL_W * M_TOTAL / 4 + 255) / 256, blk, 0, stream>>>(
        part, xdblT, XDBL_W * M_TOTAL);

    // 4) sp_T = softplus(W_dt @ dt_rawT + bias)  [1280][4096]
    gemm_tn<0, 1, 2><<<dim3(M_TOTAL / BN, D_INNER / BM), blk, 0, stream>>>(
        W_dt, xdblT, spT, D_INNER, M_TOTAL, DT_RANK, DT_RANK, M_TOTAL, M_TOTAL,
        dt_bias);

    // 5a) chunk-local (h_end, P) for chunks 0..2   (2560*3 waves)
    scan_part1<<<BATCH * D_INNER * (NCHUNK - 1), 64, 0, stream>>>(
        xdblT, spT, A_log, uT, rec);

    // 5b) per-chunk y scan with combined h_start   (2560*4 waves)
    scan_part3<<<BATCH * D_INNER * NCHUNK, 64, 0, stream>>>(
        gT, xdblT, spT, A_log, D_skip, rec, uT);

    // 5c) transpose y: uT [1280][4096] -> yN [4096][1280]
    transpose_kernel<<<dim3(M_TOTAL / 32, D_INNER / 32), blk, 0, stream>>>(uT, yN);

    // 6) out = y @ W_out^T                [4096][640]   (split-bf16 MFMA)
    gemm_mfma<0><<<dim3(D_MODEL / 128, M_TOTAL / 128), blk, 0, stream>>>(
        yN, W_out, out, M_TOTAL, D_MODEL, D_INNER, D_INNER, D_INNER, D_MODEL);
}